// Round 6
// baseline (300.599 us; speedup 1.0000x reference)
//
#include <hip/hip_runtime.h>
#include <hip/hip_bf16.h>

// Problem constants
#define B_  8
#define D_  256
#define N_  2048
#define M_  2048
#define H_  4
#define DH_ 64
#define D2_ 512

// 0.125 (1/sqrt(DH)) * log2(e), folded into Wq/bq so QK^T MFMA output is
// directly the exp2 argument.
#define SCL_QK 0.1803368801f

typedef unsigned short ushort_t;
typedef __attribute__((ext_vector_type(8))) short bf16x8;
typedef __attribute__((ext_vector_type(4))) short bf16x4;
typedef __attribute__((ext_vector_type(4))) float f32x4;

// Packed f32->bf16 RNE conversion (no builtin on gfx950 - T12 recipe).
__device__ __forceinline__ unsigned cvtpk(float a, float b) {
  unsigned r;
  asm("v_cvt_pk_bf16_f32 %0, %1, %2" : "=v"(r) : "v"(a), "v"(b));
  return r;
}
__device__ __forceinline__ ushort_t f2bf1(float x) {
  return (ushort_t)cvtpk(x, x);
}
__device__ __forceinline__ float bf2f(ushort_t h) {
  union { unsigned u; float f; } c; c.u = ((unsigned)h) << 16; return c.f;
}
__device__ __forceinline__ uint2 pack4(float a, float b, float c, float d) {
  uint2 r; r.x = cvtpk(a, b); r.y = cvtpk(c, d); return r;
}

// ---------------------------------------------------------------------------
// MFMA GEMM core: 128x128 tile, 4 waves (2x2), per-wave 64x64 (4x4 frags).
// A bf16 [O][K] row-major; Bt bf16 [N][LDB] (k fastest). No LDS: fragments
// stream straight from global (operands are L2-resident).
// D[o][n]: o = m0 + 16*fm + 4*lg + r, n = n0 + 16*fn + lq.
// ---------------------------------------------------------------------------
template <int K, int LDB>
__device__ __forceinline__ void mfma_core(const ushort_t* __restrict__ Arow,
                                          const ushort_t* __restrict__ Brow,
                                          f32x4 acc[4][4], int lg) {
#pragma unroll 2
  for (int k0 = 0; k0 < K; k0 += 32) {
    bf16x8 af[4], bfr[4];
#pragma unroll
    for (int f = 0; f < 4; ++f)
      af[f] = *(const bf16x8*)&Arow[(size_t)16 * f * K + k0 + lg * 8];
#pragma unroll
    for (int f = 0; f < 4; ++f)
      bfr[f] = *(const bf16x8*)&Brow[(size_t)16 * f * LDB + k0 + lg * 8];
#pragma unroll
    for (int fm = 0; fm < 4; ++fm)
#pragma unroll
      for (int fn = 0; fn < 4; ++fn)
        acc[fm][fn] = __builtin_amdgcn_mfma_f32_16x16x32_bf16(
            af[fm], bfr[fn], acc[fm][fn], 0, 0, 0);
  }
}

#define GEMM_PREAMBLE()                                   \
  const int t = threadIdx.x, lane = t & 63, wv = t >> 6;  \
  const int wm = wv >> 1, wn = wv & 1;                    \
  const int lq = lane & 15, lg = lane >> 4;               \
  const int m0 = blockIdx.y * 128 + wm * 64;              \
  const int n0 = blockIdx.x * 128 + wn * 64;              \
  f32x4 acc[4][4];                                        \
  _Pragma("unroll") for (int i = 0; i < 4; ++i)           \
  _Pragma("unroll") for (int j = 0; j < 4; ++j)           \
      acc[i][j] = (f32x4){0.f, 0.f, 0.f, 0.f};

// ---------------------------------------------------------------------------
// 0) Convert weights to bf16. Wq pre-scaled by SCL_QK. Wm gets its COLUMNS
//    permuted to head-major (c' = h*64+dh <- c = dh*4+h).
// grid: 2560 x 256
// ---------------------------------------------------------------------------
__global__ __launch_bounds__(256) void prep_weights(
    const float* __restrict__ Wq, const float* __restrict__ Wk,
    const float* __restrict__ Wv, const float* __restrict__ Wm,
    const float* __restrict__ W1, const float* __restrict__ W2,
    ushort_t* __restrict__ Wqb, ushort_t* __restrict__ Wkb,
    ushort_t* __restrict__ Wvb, ushort_t* __restrict__ Wmb,
    ushort_t* __restrict__ W1b, ushort_t* __restrict__ W2b) {
  const int idx = blockIdx.x * 256 + threadIdx.x;
  if (idx < 65536) {
    Wqb[idx] = f2bf1(Wq[idx] * SCL_QK);
  } else if (idx < 131072) {
    int j = idx - 65536; Wkb[j] = f2bf1(Wk[j]);
  } else if (idx < 196608) {
    int j = idx - 131072; Wvb[j] = f2bf1(Wv[j]);
  } else if (idx < 262144) {
    int j = idx - 196608;
    int e = j >> 8, cp = j & 255;
    int h = cp >> 6, dh = cp & 63;
    Wmb[j] = f2bf1(Wm[e * 256 + dh * 4 + h]);
  } else if (idx < 524288) {
    int j = idx - 262144; W1b[j] = f2bf1(W1[j]);
  } else if (idx < 655360) {
    int j = idx - 524288; W2b[j] = f2bf1(W2[j]);
  }
}

// ---------------------------------------------------------------------------
// 0.5) Transpose x -> cat_t[:, :256] (ld 512) and source -> st (ld 256), bf16.
// grid: (32, 4, 16) ; z: b = z&7, which = z>>3
// ---------------------------------------------------------------------------
__global__ __launch_bounds__(256) void transpose_in(
    const float* __restrict__ x, const float* __restrict__ source,
    ushort_t* __restrict__ cat_t, ushort_t* __restrict__ st) {
  __shared__ float T[64][65];
  const int t = threadIdx.x;
  const int b = blockIdx.z & 7, which = blockIdx.z >> 3;
  const float* sb = (which ? source : x) + (size_t)b * D_ * N_;
  ushort_t* dst = which ? st + (size_t)b * N_ * 256 : cat_t + (size_t)b * N_ * 512;
  const int ldc = which ? 256 : 512;
  const int d0 = blockIdx.y * 64, n0 = blockIdx.x * 64;
  const int nn = t & 63, dd = t >> 6;
#pragma unroll
  for (int p = 0; p < 16; ++p)
    T[dd + 4 * p][nn] = sb[(size_t)(d0 + dd + 4 * p) * N_ + n0 + nn];
  __syncthreads();
  const int dg = t & 7, nr = t >> 3;
#pragma unroll
  for (int p = 0; p < 2; ++p) {
    int n = nr + 32 * p;
    uint4 pv;
    pv.x = cvtpk(T[dg * 8 + 0][n], T[dg * 8 + 1][n]);
    pv.y = cvtpk(T[dg * 8 + 2][n], T[dg * 8 + 3][n]);
    pv.z = cvtpk(T[dg * 8 + 4][n], T[dg * 8 + 5][n]);
    pv.w = cvtpk(T[dg * 8 + 6][n], T[dg * 8 + 7][n]);
    *(uint4*)&dst[(size_t)(n0 + n) * ldc + d0 + dg * 8] = pv;
  }
}

// ---------------------------------------------------------------------------
// 1a) Q projection: Qt[bh][n][64] bf16 (pre-scaled by SCL_QK). grid (16,2,8)
// ---------------------------------------------------------------------------
__global__ __launch_bounds__(256) void q_mfma(
    const ushort_t* __restrict__ Wqb, const float* __restrict__ bq,
    const ushort_t* __restrict__ cat_t, ushort_t* __restrict__ Qt) {
  GEMM_PREAMBLE()
  const int b = blockIdx.z;
  const ushort_t* Arow = Wqb + (size_t)(m0 + lq) * 256;
  const ushort_t* Brow = cat_t + ((size_t)b * N_ + n0 + lq) * 512;
  mfma_core<256, 512>(Arow, Brow, acc, lg);
  ushort_t* Qb = Qt + (size_t)b * 4 * N_ * 64;
#pragma unroll
  for (int fm = 0; fm < 4; ++fm) {
    const int o0 = m0 + 16 * fm + 4 * lg;
    const int hh = o0 >> 6, dl = o0 & 63;
    float bb[4];
#pragma unroll
    for (int r = 0; r < 4; ++r) bb[r] = bq[o0 + r] * SCL_QK;
#pragma unroll
    for (int fn = 0; fn < 4; ++fn) {
      const int n = n0 + 16 * fn + lq;
      uint2 pv = pack4(acc[fm][fn][0] + bb[0], acc[fm][fn][1] + bb[1],
                       acc[fm][fn][2] + bb[2], acc[fm][fn][3] + bb[3]);
      *(uint2*)&Qb[((size_t)hh * N_ + n) * 64 + dl] = pv;
    }
  }
}

// ---------------------------------------------------------------------------
// 1b) K,V projections from source: Kt[bh][n][64]; Vt[bh][64][m].
// grid (16, 2, 16) ; z: b = z>>1, w = z&1 (0=K, 1=V)
// ---------------------------------------------------------------------------
__global__ __launch_bounds__(256) void kv_mfma(
    const ushort_t* __restrict__ Wkb, const ushort_t* __restrict__ Wvb,
    const float* __restrict__ bk, const float* __restrict__ bv,
    const ushort_t* __restrict__ st, ushort_t* __restrict__ Kt,
    ushort_t* __restrict__ Vt) {
  const int b = blockIdx.z >> 1, w = blockIdx.z & 1;
  GEMM_PREAMBLE()
  const ushort_t* A = w ? Wvb : Wkb;
  const float* bias = w ? bv : bk;
  const ushort_t* Arow = A + (size_t)(m0 + lq) * 256;
  const ushort_t* Brow = st + ((size_t)b * N_ + n0 + lq) * 256;
  mfma_core<256, 256>(Arow, Brow, acc, lg);
  if (w == 0) {
    ushort_t* Kb = Kt + (size_t)b * 4 * N_ * 64;
#pragma unroll
    for (int fm = 0; fm < 4; ++fm) {
      const int o0 = m0 + 16 * fm + 4 * lg;
      const int hh = o0 >> 6, dl = o0 & 63;
      float bb[4];
#pragma unroll
      for (int r = 0; r < 4; ++r) bb[r] = bias[o0 + r];
#pragma unroll
      for (int fn = 0; fn < 4; ++fn) {
        const int n = n0 + 16 * fn + lq;
        uint2 pv = pack4(acc[fm][fn][0] + bb[0], acc[fm][fn][1] + bb[1],
                         acc[fm][fn][2] + bb[2], acc[fm][fn][3] + bb[3]);
        *(uint2*)&Kb[((size_t)hh * N_ + n) * 64 + dl] = pv;
      }
    }
  } else {
    ushort_t* Vb = Vt + (size_t)b * 256 * N_;
#pragma unroll
    for (int fm = 0; fm < 4; ++fm) {
      const int o0 = m0 + 16 * fm + 4 * lg;
      float bb[4];
#pragma unroll
      for (int r = 0; r < 4; ++r) bb[r] = bias[o0 + r];
#pragma unroll
      for (int fn = 0; fn < 4; ++fn) {
        const int n = n0 + 16 * fn + lq;
#pragma unroll
        for (int r = 0; r < 4; ++r)
          Vb[(size_t)(o0 + r) * N_ + n] = f2bf1(acc[fm][fn][r] + bb[r]);
      }
    }
  }
}

// ---------------------------------------------------------------------------
// 2) MFMA flash attention, max-free softmax (P = 2^s, Q pre-scaled).
//    l computed by MFMA via a ones-row appended to V (Vs rows 64..79).
//    XCD-swizzled 1D grid: each XCD owns 4 complete (b,h) groups.
// grid: 1024, 256 threads
// ---------------------------------------------------------------------------
__global__ __launch_bounds__(256) void attn_mfma(
    const ushort_t* __restrict__ Qt, const ushort_t* __restrict__ Kt,
    const ushort_t* __restrict__ Vt, ushort_t* __restrict__ msgT) {
  __shared__ __align__(16) ushort_t Ks[64 * 64];  // [key][dh] swz
  __shared__ __align__(16) ushort_t Vs[80 * 64];  // [dh][key] swz + ones rows
  __shared__ __align__(16) ushort_t Ps[64 * 64];  // [q][key]  swz
  const int t = threadIdx.x;
  const int lane = t & 63, wq = t >> 6;
  // XCD swizzle: flat -> (xcd owns 128 consecutive logical ids)
  const int flat = blockIdx.x;
  const int logical = (flat & 7) * 128 + (flat >> 3);
  const int qt = logical & 31, h = (logical >> 5) & 3, b = logical >> 7;
  const int bh = b * H_ + h;
  const size_t base = (size_t)bh * 64 * N_;
  const int n00 = qt * 64;
  const int lq = lane & 15, lg = lane >> 4;
  const int qrow = wq * 16 + lq;
  const int sw = (lq & 7) * 8;

  // ones rows for the l-sum MFMA: Vs row 64 = 1.0, rows 65..79 = 0.
  // (row content uniform => swizzled layout == linear layout)
  {
    const int row = 64 + (t >> 4);
    const int c4 = (t & 15) * 4;
    const unsigned fill = (row == 64) ? 0x3F803F80u : 0u;
    uint2 iv; iv.x = fill; iv.y = fill;
    *(uint2*)&Vs[row * 64 + c4] = iv;
  }

  bf16x8 qf0, qf1;
  {
    const ushort_t* qp = Qt + base + (size_t)(n00 + qrow) * 64 + lg * 8;
    qf0 = *(const bf16x8*)qp;
    qf1 = *(const bf16x8*)(qp + 32);
  }
  f32x4 o0 = {0.f, 0.f, 0.f, 0.f}, o1 = o0, o2 = o0, o3 = o0, l4 = o0;
  const int sdg = (t & 7) * 8, srw = t >> 3;

  for (int m0 = 0; m0 < M_; m0 += 64) {
    // ---- stage K tile [key][dh] and V tile [dh][key] (bf16, swizzled) ----
#pragma unroll
    for (int p = 0; p < 2; ++p) {
      int r = srw + 32 * p;
      int wsw = (r & 7) * 8;
      *(bf16x8*)&Ks[r * 64 + (sdg ^ wsw)] =
          *(const bf16x8*)(Kt + base + (size_t)(m0 + r) * 64 + sdg);
      *(bf16x8*)&Vs[r * 64 + (sdg ^ wsw)] =
          *(const bf16x8*)(Vt + base + (size_t)r * N_ + m0 + sdg);
    }
    __syncthreads();

    // ---- S^T = K . Q^T (rows = keys, cols = queries); s is exp2 arg ----
    f32x4 s0 = {0.f, 0.f, 0.f, 0.f}, s1 = s0, s2 = s0, s3 = s0;
#pragma unroll
    for (int kt = 0; kt < 2; ++kt) {
      const int dh0 = (lg * 8 + 32 * kt) ^ sw;
      const bf16x8 qb = kt ? qf1 : qf0;
      s0 = __builtin_amdgcn_mfma_f32_16x16x32_bf16(
          *(const bf16x8*)&Ks[lq * 64 + dh0], qb, s0, 0, 0, 0);
      s1 = __builtin_amdgcn_mfma_f32_16x16x32_bf16(
          *(const bf16x8*)&Ks[(16 + lq) * 64 + dh0], qb, s1, 0, 0, 0);
      s2 = __builtin_amdgcn_mfma_f32_16x16x32_bf16(
          *(const bf16x8*)&Ks[(32 + lq) * 64 + dh0], qb, s2, 0, 0, 0);
      s3 = __builtin_amdgcn_mfma_f32_16x16x32_bf16(
          *(const bf16x8*)&Ks[(48 + lq) * 64 + dh0], qb, s3, 0, 0, 0);
    }

    // ---- P = 2^s, packed to bf16 LDS via cvt_pk (no max, no rescale) ----
#define PSTORE(SF, KF)                                                    \
    {                                                                     \
      uint2 pv;                                                           \
      pv.x = cvtpk(exp2f(SF[0]), exp2f(SF[1]));                           \
      pv.y = cvtpk(exp2f(SF[2]), exp2f(SF[3]));                           \
      *(uint2*)&Ps[qrow * 64 + ((16 * (KF) + 4 * lg) ^ sw)] = pv;         \
    }
    PSTORE(s0, 0) PSTORE(s1, 1) PSTORE(s2, 2) PSTORE(s3, 3)
#undef PSTORE
    asm volatile("s_waitcnt lgkmcnt(0)" ::: "memory");

    // ---- O^T += V^T . P^T ; l4 += ones . P^T (row 64) ----
#pragma unroll
    for (int kt = 0; kt < 2; ++kt) {
      const int k0 = (lg * 8 + 32 * kt) ^ sw;
      const bf16x8 pb = *(const bf16x8*)&Ps[qrow * 64 + k0];
      o0 = __builtin_amdgcn_mfma_f32_16x16x32_bf16(
          *(const bf16x8*)&Vs[lq * 64 + k0], pb, o0, 0, 0, 0);
      o1 = __builtin_amdgcn_mfma_f32_16x16x32_bf16(
          *(const bf16x8*)&Vs[(16 + lq) * 64 + k0], pb, o1, 0, 0, 0);
      o2 = __builtin_amdgcn_mfma_f32_16x16x32_bf16(
          *(const bf16x8*)&Vs[(32 + lq) * 64 + k0], pb, o2, 0, 0, 0);
      o3 = __builtin_amdgcn_mfma_f32_16x16x32_bf16(
          *(const bf16x8*)&Vs[(48 + lq) * 64 + k0], pb, o3, 0, 0, 0);
      l4 = __builtin_amdgcn_mfma_f32_16x16x32_bf16(
          *(const bf16x8*)&Vs[(64 + lq) * 64 + k0], pb, l4, 0, 0, 0);
    }
    __syncthreads();
  }

  // l for query lq lives in lane lq (lg=0), reg 0.
  const float lsum = __shfl(l4[0], lq);
  const float inv = 1.f / lsum;

  // ---- write msgT[b][n][h*64 + dh] bf16 (head-major; Wm cols permuted) ----
  ushort_t* mp = msgT + ((size_t)b * N_ + n00 + qrow) * 256 + h * 64;
  uint2 pv;
  pv = pack4(o0[0] * inv, o0[1] * inv, o0[2] * inv, o0[3] * inv);
  *(uint2*)&mp[0 + 4 * lg] = pv;
  pv = pack4(o1[0] * inv, o1[1] * inv, o1[2] * inv, o1[3] * inv);
  *(uint2*)&mp[16 + 4 * lg] = pv;
  pv = pack4(o2[0] * inv, o2[1] * inv, o2[2] * inv, o2[3] * inv);
  *(uint2*)&mp[32 + 4 * lg] = pv;
  pv = pack4(o3[0] * inv, o3[1] * inv, o3[2] * inv, o3[3] * inv);
  *(uint2*)&mp[48 + 4 * lg] = pv;
}

// ---------------------------------------------------------------------------
// 3) merge: msg2^T -> cat_t[:, 256:] (ld 512).  grid (16, 2, 8)
// ---------------------------------------------------------------------------
__global__ __launch_bounds__(256) void merge_mfma(
    const ushort_t* __restrict__ Wmb, const float* __restrict__ bm,
    const ushort_t* __restrict__ msgT, ushort_t* __restrict__ cat_t) {
  GEMM_PREAMBLE()
  const int b = blockIdx.z;
  const ushort_t* Arow = Wmb + (size_t)(m0 + lq) * 256;
  const ushort_t* Brow = msgT + ((size_t)b * N_ + n0 + lq) * 256;
  mfma_core<256, 256>(Arow, Brow, acc, lg);
  ushort_t* ob = cat_t + (size_t)b * N_ * 512 + 256;
#pragma unroll
  for (int fm = 0; fm < 4; ++fm) {
    const int o0 = m0 + 16 * fm + 4 * lg;
    float bb[4];
#pragma unroll
    for (int r = 0; r < 4; ++r) bb[r] = bm[o0 + r];
#pragma unroll
    for (int fn = 0; fn < 4; ++fn) {
      const int n = n0 + 16 * fn + lq;
      uint2 pv = pack4(acc[fm][fn][0] + bb[0], acc[fm][fn][1] + bb[1],
                       acc[fm][fn][2] + bb[2], acc[fm][fn][3] + bb[3]);
      *(uint2*)&ob[(size_t)n * 512 + o0] = pv;
    }
  }
}

// ---------------------------------------------------------------------------
// 4) W1: h1^T = (W1 @ cat)^T -> h1t[b][n][512] bf16.  grid (16, 4, 8)
// ---------------------------------------------------------------------------
__global__ __launch_bounds__(256) void w1_mfma(
    const ushort_t* __restrict__ W1b, const float* __restrict__ b1,
    const ushort_t* __restrict__ cat_t, ushort_t* __restrict__ h1t) {
  GEMM_PREAMBLE()
  const int b = blockIdx.z;
  const ushort_t* Arow = W1b + (size_t)(m0 + lq) * 512;
  const ushort_t* Brow = cat_t + ((size_t)b * N_ + n0 + lq) * 512;
  mfma_core<512, 512>(Arow, Brow, acc, lg);
  ushort_t* ob = h1t + (size_t)b * N_ * 512;
#pragma unroll
  for (int fm = 0; fm < 4; ++fm) {
    const int o0 = m0 + 16 * fm + 4 * lg;
    float bb[4];
#pragma unroll
    for (int r = 0; r < 4; ++r) bb[r] = b1[o0 + r];
#pragma unroll
    for (int fn = 0; fn < 4; ++fn) {
      const int n = n0 + 16 * fn + lq;
      uint2 pv = pack4(acc[fm][fn][0] + bb[0], acc[fm][fn][1] + bb[1],
                       acc[fm][fn][2] + bb[2], acc[fm][fn][3] + bb[3]);
      *(uint2*)&ob[(size_t)n * 512 + o0] = pv;
    }
  }
}

// ---------------------------------------------------------------------------
// 5) InstanceNorm stats on h1t
// ---------------------------------------------------------------------------
__global__ __launch_bounds__(256) void zero_stats(float* __restrict__ s) {
  s[blockIdx.x * 256 + threadIdx.x] = 0.f;  // grid 32 -> 8192 floats
}

// grid (8 nchunk, 8 cchunk, 8 b)
__global__ __launch_bounds__(256) void stats_partial(
    const ushort_t* __restrict__ h1t, float* __restrict__ ssum,
    float* __restrict__ ssq) {
  const int t = threadIdx.x;
  const int c = blockIdx.y * 64 + (t & 63);
  const int b = blockIdx.z;
  const int nbase = blockIdx.x * 256 + (t >> 6) * 64;
  const ushort_t* p = h1t + (size_t)b * N_ * 512;
  float s = 0.f, ss = 0.f;
  for (int i = 0; i < 64; ++i) {
    float v = bf2f(p[(size_t)(nbase + i) * 512 + c]);
    s += v; ss += v * v;
  }
  __shared__ float rs[4][64], rq[4][64];
  const int wv = t >> 6;
  rs[wv][t & 63] = s; rq[wv][t & 63] = ss;
  __syncthreads();
  if (t < 64) {
    float S = rs[0][t] + rs[1][t] + rs[2][t] + rs[3][t];
    float Q = rq[0][t] + rq[1][t] + rq[2][t] + rq[3][t];
    atomicAdd(&ssum[b * 512 + blockIdx.y * 64 + t], S);
    atomicAdd(&ssq[b * 512 + blockIdx.y * 64 + t], Q);
  }
}

__global__ __launch_bounds__(256) void finalize_stats(
    const float* __restrict__ ssum, const float* __restrict__ ssq,
    float* __restrict__ mean, float* __restrict__ istd) {
  const int i = blockIdx.x * 256 + threadIdx.x;  // grid 16 -> 4096
  float mn = ssum[i] * (1.f / N_);
  float var = ssq[i] * (1.f / N_) - mn * mn;
  mean[i] = mn;
  istd[i] = rsqrtf(var + 1e-5f);
}

// ---------------------------------------------------------------------------
// 6) normalize+relu: h1n = relu((h1t - mean) * istd) bf16.  grid 4096
// ---------------------------------------------------------------------------
__global__ __launch_bounds__(256) void normalize_h1(
    const ushort_t* __restrict__ h1t, const float* __restrict__ mean,
    const float* __restrict__ istd, ushort_t* __restrict__ h1n) {
  const size_t ci = (size_t)blockIdx.x * 256 + threadIdx.x;
  const size_t basei = ci * 8;
  const int c0 = (int)(basei & 511);
  const size_t row = basei >> 9;  // b*N + n
  const int b = (int)(row >> 11);
  const float* mp = mean + b * 512 + c0;
  const float* ip = istd + b * 512 + c0;
  union { bf16x8 v; ushort_t u[8]; } in;
  in.v = *(const bf16x8*)&h1t[basei];
  float g[8];
#pragma unroll
  for (int j = 0; j < 8; ++j)
    g[j] = fmaxf((bf2f(in.u[j]) - mp[j]) * ip[j], 0.f);
  uint4 pv;
  pv.x = cvtpk(g[0], g[1]);
  pv.y = cvtpk(g[2], g[3]);
  pv.z = cvtpk(g[4], g[5]);
  pv.w = cvtpk(g[6], g[7]);
  *(uint4*)&h1n[basei] = pv;
}

// ---------------------------------------------------------------------------
// 7) W2: out = W2 @ h1n + b2, f32 [b][256][N].  grid (16, 2, 8)
// ---------------------------------------------------------------------------
__global__ __launch_bounds__(256) void w2_mfma(
    const ushort_t* __restrict__ W2b, const float* __restrict__ b2,
    const ushort_t* __restrict__ h1n, float* __restrict__ out) {
  GEMM_PREAMBLE()
  const int b = blockIdx.z;
  const ushort_t* Arow = W2b + (size_t)(m0 + lq) * 512;
  const ushort_t* Brow = h1n + ((size_t)b * N_ + n0 + lq) * 512;
  mfma_core<512, 512>(Arow, Brow, acc, lg);
  float* ob = out + (size_t)b * D_ * N_;
#pragma unroll
  for (int fm = 0; fm < 4; ++fm) {
    const int o0 = m0 + 16 * fm + 4 * lg;
    float bb[4];
#pragma unroll
    for (int r = 0; r < 4; ++r) bb[r] = b2[o0 + r];
#pragma unroll
    for (int fn = 0; fn < 4; ++fn) {
      const int n = n0 + 16 * fn + lq;
#pragma unroll
      for (int r = 0; r < 4; ++r)
        ob[(size_t)(o0 + r) * N_ + n] = acc[fm][fn][r] + bb[r];
    }
  }
}

// ---------------------------------------------------------------------------
extern "C" void kernel_launch(void* const* d_in, const int* in_sizes, int n_in,
                              void* d_out, int out_size, void* d_ws,
                              size_t ws_size, hipStream_t stream) {
  const float* x = (const float*)d_in[0];
  const float* source = (const float*)d_in[1];
  const float* Wq = (const float*)d_in[2];
  const float* bq = (const float*)d_in[3];
  const float* Wk = (const float*)d_in[4];
  const float* bk = (const float*)d_in[5];
  const float* Wv = (const float*)d_in[6];
  const float* bv = (const float*)d_in[7];
  const float* Wm = (const float*)d_in[8];
  const float* bm = (const float*)d_in[9];
  const float* W1 = (const float*)d_in[10];
  const float* b1 = (const float*)d_in[11];
  const float* W2 = (const float*)d_in[12];
  const float* b2 = (const float*)d_in[13];
  float* out = (float*)d_out;

  char* w = (char*)d_ws;
  size_t off = 0;
  auto alloc = [&](size_t bytes) {
    void* p = w + off;
    off = (off + bytes + 255) & ~(size_t)255;
    return p;
  };
  ushort_t* cat_t = (ushort_t*)alloc((size_t)B_ * N_ * 512 * 2);  // x^T | msg2^T
  ushort_t* st    = (ushort_t*)alloc((size_t)B_ * N_ * 256 * 2);
  ushort_t* Qt    = (ushort_t*)alloc((size_t)B_ * 4 * N_ * 64 * 2);
  ushort_t* Kt    = (ushort_t*)alloc((size_t)B_ * 4 * N_ * 64 * 2);
  ushort_t* Vt    = (ushort_t*)alloc((size_t)B_ * 256 * N_ * 2);
  ushort_t* msgT  = (ushort_t*)alloc((size_t)B_ * N_ * 256 * 2);
  ushort_t* h1t   = (ushort_t*)alloc((size_t)B_ * N_ * 512 * 2);
  ushort_t* h1n   = (ushort_t*)alloc((size_t)B_ * N_ * 512 * 2);
  float* ssum = (float*)alloc(4096 * 4);
  float* ssq  = (float*)alloc(4096 * 4);
  float* mean = (float*)alloc(4096 * 4);
  float* istd = (float*)alloc(4096 * 4);
  ushort_t* Wqb = (ushort_t*)alloc(65536 * 2);
  ushort_t* Wkb = (ushort_t*)alloc(65536 * 2);
  ushort_t* Wvb = (ushort_t*)alloc(65536 * 2);
  ushort_t* Wmb = (ushort_t*)alloc(65536 * 2);
  ushort_t* W1b = (ushort_t*)alloc(262144 * 2);
  ushort_t* W2b = (ushort_t*)alloc(131072 * 2);

  prep_weights<<<2560, 256, 0, stream>>>(Wq, Wk, Wv, Wm, W1, W2, Wqb, Wkb,
                                         Wvb, Wmb, W1b, W2b);
  transpose_in<<<dim3(32, 4, 16), 256, 0, stream>>>(x, source, cat_t, st);
  zero_stats<<<32, 256, 0, stream>>>(ssum);  // ssum+ssq contiguous (8192 f32)
  q_mfma<<<dim3(16, 2, 8), 256, 0, stream>>>(Wqb, bq, cat_t, Qt);
  kv_mfma<<<dim3(16, 2, 16), 256, 0, stream>>>(Wkb, Wvb, bk, bv, st, Kt, Vt);
  attn_mfma<<<dim3(1024), 256, 0, stream>>>(Qt, Kt, Vt, msgT);
  merge_mfma<<<dim3(16, 2, 8), 256, 0, stream>>>(Wmb, bm, msgT, cat_t);
  w1_mfma<<<dim3(16, 4, 8), 256, 0, stream>>>(W1b, b1, cat_t, h1t);
  stats_partial<<<dim3(8, 8, 8), 256, 0, stream>>>(h1t, ssum, ssq);
  finalize_stats<<<16, 256, 0, stream>>>(ssum, ssq, mean, istd);
  normalize_h1<<<4096, 256, 0, stream>>>(h1t, mean, istd, h1n);
  w2_mfma<<<dim3(16, 2, 8), 256, 0, stream>>>(W2b, b2, h1n, out);
}

// Round 8
// 286.875 us; speedup vs baseline: 1.0478x; 1.0478x over previous
//
#include <hip/hip_runtime.h>
#include <hip/hip_bf16.h>

// Problem constants
#define B_  8
#define D_  256
#define N_  2048
#define M_  2048
#define H_  4
#define DH_ 64
#define D2_ 512

// 0.125 (1/sqrt(DH)) * log2(e), folded into Wq/bq so QK^T MFMA output is
// directly the exp2 argument.
#define SCL_QK 0.1803368801f

typedef unsigned short ushort_t;
typedef __attribute__((ext_vector_type(8))) short bf16x8;
typedef __attribute__((ext_vector_type(4))) short bf16x4;
typedef __attribute__((ext_vector_type(4))) float f32x4;

// Packed f32->bf16 RNE conversion (no builtin on gfx950 - T12 recipe).
__device__ __forceinline__ unsigned cvtpk(float a, float b) {
  unsigned r;
  asm("v_cvt_pk_bf16_f32 %0, %1, %2" : "=v"(r) : "v"(a), "v"(b));
  return r;
}
__device__ __forceinline__ ushort_t f2bf1(float x) {
  return (ushort_t)cvtpk(x, x);
}
__device__ __forceinline__ float bf2f(ushort_t h) {
  union { unsigned u; float f; } c; c.u = ((unsigned)h) << 16; return c.f;
}
__device__ __forceinline__ uint2 pack4(float a, float b, float c, float d) {
  uint2 r; r.x = cvtpk(a, b); r.y = cvtpk(c, d); return r;
}

// Async global->LDS, 16B per lane. LDS dest = wave-uniform base + lane*16.
__device__ __forceinline__ void gload16(const ushort_t* g, ushort_t* l) {
  __builtin_amdgcn_global_load_lds(
      (const __attribute__((address_space(1))) unsigned*)g,
      (__attribute__((address_space(3))) unsigned*)l, 16, 0, 0);
}

// ---------------------------------------------------------------------------
// MFMA GEMM core: 128x128 tile, 4 waves (2x2), per-wave 64x64 (4x4 frags).
// A bf16 [O][K] row-major; Bt bf16 [N][LDB] (k fastest). No LDS: fragments
// stream straight from global (operands are L2-resident).
// D[o][n]: o = m0 + 16*fm + 4*lg + r, n = n0 + 16*fn + lq.
// ---------------------------------------------------------------------------
template <int K, int LDB>
__device__ __forceinline__ void mfma_core(const ushort_t* __restrict__ Arow,
                                          const ushort_t* __restrict__ Brow,
                                          f32x4 acc[4][4], int lg) {
#pragma unroll 2
  for (int k0 = 0; k0 < K; k0 += 32) {
    bf16x8 af[4], bfr[4];
#pragma unroll
    for (int f = 0; f < 4; ++f)
      af[f] = *(const bf16x8*)&Arow[(size_t)16 * f * K + k0 + lg * 8];
#pragma unroll
    for (int f = 0; f < 4; ++f)
      bfr[f] = *(const bf16x8*)&Brow[(size_t)16 * f * LDB + k0 + lg * 8];
#pragma unroll
    for (int fm = 0; fm < 4; ++fm)
#pragma unroll
      for (int fn = 0; fn < 4; ++fn)
        acc[fm][fn] = __builtin_amdgcn_mfma_f32_16x16x32_bf16(
            af[fm], bfr[fn], acc[fm][fn], 0, 0, 0);
  }
}

#define GEMM_PREAMBLE()                                   \
  const int t = threadIdx.x, lane = t & 63, wv = t >> 6;  \
  const int wm = wv >> 1, wn = wv & 1;                    \
  const int lq = lane & 15, lg = lane >> 4;               \
  const int m0 = blockIdx.y * 128 + wm * 64;              \
  const int n0 = blockIdx.x * 128 + wn * 64;              \
  f32x4 acc[4][4];                                        \
  _Pragma("unroll") for (int i = 0; i < 4; ++i)           \
  _Pragma("unroll") for (int j = 0; j < 4; ++j)           \
      acc[i][j] = (f32x4){0.f, 0.f, 0.f, 0.f};

// ---------------------------------------------------------------------------
// 0) Convert weights to bf16. Wq pre-scaled by SCL_QK. Wm gets its COLUMNS
//    permuted to head-major (c' = h*64+dh <- c = dh*4+h).
// grid: 2560 x 256
// ---------------------------------------------------------------------------
__global__ __launch_bounds__(256) void prep_weights(
    const float* __restrict__ Wq, const float* __restrict__ Wk,
    const float* __restrict__ Wv, const float* __restrict__ Wm,
    const float* __restrict__ W1, const float* __restrict__ W2,
    ushort_t* __restrict__ Wqb, ushort_t* __restrict__ Wkb,
    ushort_t* __restrict__ Wvb, ushort_t* __restrict__ Wmb,
    ushort_t* __restrict__ W1b, ushort_t* __restrict__ W2b) {
  const int idx = blockIdx.x * 256 + threadIdx.x;
  if (idx < 65536) {
    Wqb[idx] = f2bf1(Wq[idx] * SCL_QK);
  } else if (idx < 131072) {
    int j = idx - 65536; Wkb[j] = f2bf1(Wk[j]);
  } else if (idx < 196608) {
    int j = idx - 131072; Wvb[j] = f2bf1(Wv[j]);
  } else if (idx < 262144) {
    int j = idx - 196608;
    int e = j >> 8, cp = j & 255;
    int h = cp >> 6, dh = cp & 63;
    Wmb[j] = f2bf1(Wm[e * 256 + dh * 4 + h]);
  } else if (idx < 524288) {
    int j = idx - 262144; W1b[j] = f2bf1(W1[j]);
  } else if (idx < 655360) {
    int j = idx - 524288; W2b[j] = f2bf1(W2[j]);
  }
}

// ---------------------------------------------------------------------------
// 0.5) Transpose x -> cat_t[:, :256] (ld 512) and source -> st (ld 256), bf16.
// grid: (32, 4, 16) ; z: b = z&7, which = z>>3
// ---------------------------------------------------------------------------
__global__ __launch_bounds__(256) void transpose_in(
    const float* __restrict__ x, const float* __restrict__ source,
    ushort_t* __restrict__ cat_t, ushort_t* __restrict__ st) {
  __shared__ float T[64][65];
  const int t = threadIdx.x;
  const int b = blockIdx.z & 7, which = blockIdx.z >> 3;
  const float* sb = (which ? source : x) + (size_t)b * D_ * N_;
  ushort_t* dst = which ? st + (size_t)b * N_ * 256 : cat_t + (size_t)b * N_ * 512;
  const int ldc = which ? 256 : 512;
  const int d0 = blockIdx.y * 64, n0 = blockIdx.x * 64;
  const int nn = t & 63, dd = t >> 6;
#pragma unroll
  for (int p = 0; p < 16; ++p)
    T[dd + 4 * p][nn] = sb[(size_t)(d0 + dd + 4 * p) * N_ + n0 + nn];
  __syncthreads();
  const int dg = t & 7, nr = t >> 3;
#pragma unroll
  for (int p = 0; p < 2; ++p) {
    int n = nr + 32 * p;
    uint4 pv;
    pv.x = cvtpk(T[dg * 8 + 0][n], T[dg * 8 + 1][n]);
    pv.y = cvtpk(T[dg * 8 + 2][n], T[dg * 8 + 3][n]);
    pv.z = cvtpk(T[dg * 8 + 4][n], T[dg * 8 + 5][n]);
    pv.w = cvtpk(T[dg * 8 + 6][n], T[dg * 8 + 7][n]);
    *(uint4*)&dst[(size_t)(n0 + n) * ldc + d0 + dg * 8] = pv;
  }
}

// ---------------------------------------------------------------------------
// 1a) Q projection: Qt[bh][n][64] bf16 (pre-scaled by SCL_QK). grid (16,2,8)
// ---------------------------------------------------------------------------
__global__ __launch_bounds__(256) void q_mfma(
    const ushort_t* __restrict__ Wqb, const float* __restrict__ bq,
    const ushort_t* __restrict__ cat_t, ushort_t* __restrict__ Qt) {
  GEMM_PREAMBLE()
  const int b = blockIdx.z;
  const ushort_t* Arow = Wqb + (size_t)(m0 + lq) * 256;
  const ushort_t* Brow = cat_t + ((size_t)b * N_ + n0 + lq) * 512;
  mfma_core<256, 512>(Arow, Brow, acc, lg);
  ushort_t* Qb = Qt + (size_t)b * 4 * N_ * 64;
#pragma unroll
  for (int fm = 0; fm < 4; ++fm) {
    const int o0 = m0 + 16 * fm + 4 * lg;
    const int hh = o0 >> 6, dl = o0 & 63;
    float bb[4];
#pragma unroll
    for (int r = 0; r < 4; ++r) bb[r] = bq[o0 + r] * SCL_QK;
#pragma unroll
    for (int fn = 0; fn < 4; ++fn) {
      const int n = n0 + 16 * fn + lq;
      uint2 pv = pack4(acc[fm][fn][0] + bb[0], acc[fm][fn][1] + bb[1],
                       acc[fm][fn][2] + bb[2], acc[fm][fn][3] + bb[3]);
      *(uint2*)&Qb[((size_t)hh * N_ + n) * 64 + dl] = pv;
    }
  }
}

// ---------------------------------------------------------------------------
// 1b) K,V projections from source: Kt[bh][n][64]; Vt[bh][64][m].
// grid (16, 2, 16) ; z: b = z>>1, w = z&1 (0=K, 1=V)
// ---------------------------------------------------------------------------
__global__ __launch_bounds__(256) void kv_mfma(
    const ushort_t* __restrict__ Wkb, const ushort_t* __restrict__ Wvb,
    const float* __restrict__ bk, const float* __restrict__ bv,
    const ushort_t* __restrict__ st, ushort_t* __restrict__ Kt,
    ushort_t* __restrict__ Vt) {
  const int b = blockIdx.z >> 1, w = blockIdx.z & 1;
  GEMM_PREAMBLE()
  const ushort_t* A = w ? Wvb : Wkb;
  const float* bias = w ? bv : bk;
  const ushort_t* Arow = A + (size_t)(m0 + lq) * 256;
  const ushort_t* Brow = st + ((size_t)b * N_ + n0 + lq) * 256;
  mfma_core<256, 256>(Arow, Brow, acc, lg);
  if (w == 0) {
    ushort_t* Kb = Kt + (size_t)b * 4 * N_ * 64;
#pragma unroll
    for (int fm = 0; fm < 4; ++fm) {
      const int o0 = m0 + 16 * fm + 4 * lg;
      const int hh = o0 >> 6, dl = o0 & 63;
      float bb[4];
#pragma unroll
      for (int r = 0; r < 4; ++r) bb[r] = bias[o0 + r];
#pragma unroll
      for (int fn = 0; fn < 4; ++fn) {
        const int n = n0 + 16 * fn + lq;
        uint2 pv = pack4(acc[fm][fn][0] + bb[0], acc[fm][fn][1] + bb[1],
                         acc[fm][fn][2] + bb[2], acc[fm][fn][3] + bb[3]);
        *(uint2*)&Kb[((size_t)hh * N_ + n) * 64 + dl] = pv;
      }
    }
  } else {
    ushort_t* Vb = Vt + (size_t)b * 256 * N_;
#pragma unroll
    for (int fm = 0; fm < 4; ++fm) {
      const int o0 = m0 + 16 * fm + 4 * lg;
      float bb[4];
#pragma unroll
      for (int r = 0; r < 4; ++r) bb[r] = bias[o0 + r];
#pragma unroll
      for (int fn = 0; fn < 4; ++fn) {
        const int n = n0 + 16 * fn + lq;
#pragma unroll
        for (int r = 0; r < 4; ++r)
          Vb[(size_t)(o0 + r) * N_ + n] = f2bf1(acc[fm][fn][r] + bb[r]);
      }
    }
  }
}

// ---------------------------------------------------------------------------
// 2) MFMA flash attention, max-free softmax (P = 2^s, Q pre-scaled).
//    Double-buffered K/V staged via global_load_lds with pre-swizzled global
//    source (linear LDS dest); ONE barrier per tile. l-sum in registers.
//    LDS = 16K(K dbuf) + 16K(V dbuf) + 8K(Ps) = 40960 B -> 4 blocks/CU.
// grid: 1024 (XCD-swizzled), 256 threads
// ---------------------------------------------------------------------------
__global__ __launch_bounds__(256) void attn_mfma(
    const ushort_t* __restrict__ Qt, const ushort_t* __restrict__ Kt,
    const ushort_t* __restrict__ Vt, ushort_t* __restrict__ msgT) {
  __shared__ __align__(16) ushort_t Ks[2 * 64 * 64];  // [buf][key][dh] swz
  __shared__ __align__(16) ushort_t Vs[2 * 64 * 64];  // [buf][dh][key] swz
  __shared__ __align__(16) ushort_t Ps[64 * 64];      // [q][key] swz (wave-priv)
  const int t = threadIdx.x;
  const int lane = t & 63, wq = t >> 6;
  // XCD swizzle: each XCD owns 128 consecutive logical ids (4 full bh groups)
  const int flat = blockIdx.x;
  const int logical = (flat & 7) * 128 + (flat >> 3);
  const int qt = logical & 31, h = (logical >> 5) & 3, b = logical >> 7;
  const int bh = b * H_ + h;
  const size_t base = (size_t)bh * 64 * N_;
  const int n00 = qt * 64;
  const int lq = lane & 15, lg = lane >> 4;
  const int qrow = wq * 16 + lq;
  const int sw = (lq & 7) * 8;

  // Staging: per issue, wave covers 8 rows (64 lanes x 16B; 128B/row).
  // Lane -> row r = rowbase + (lane>>3), col-group c8 = lane&7.
  // Pre-swizzled SOURCE col = (c8 ^ (r&7))*8 so the linear LDS dest holds
  // LDS[r][c] = G[r][c ^ ((r&7)*8)] (matches the read-side XOR swizzle).
  const int r0 = wq * 16 + (lane >> 3);
  const int r1 = r0 + 8;
  const int c8 = lane & 7;
  const ushort_t* kp0 = Kt + base + (size_t)r0 * 64 + ((c8 ^ (r0 & 7)) * 8);
  const ushort_t* kp1 = Kt + base + (size_t)r1 * 64 + ((c8 ^ (r1 & 7)) * 8);
  const ushort_t* vp0 = Vt + base + (size_t)r0 * N_ + ((c8 ^ (r0 & 7)) * 8);
  const ushort_t* vp1 = Vt + base + (size_t)r1 * N_ + ((c8 ^ (r1 & 7)) * 8);
  const int wbase = wq * 1024;  // wave's 16-row LDS region (elements)

  bf16x8 qf0, qf1;
  {
    const ushort_t* qp = Qt + base + (size_t)(n00 + qrow) * 64 + lg * 8;
    qf0 = *(const bf16x8*)qp;
    qf1 = *(const bf16x8*)(qp + 32);
  }
  f32x4 o0 = {0.f, 0.f, 0.f, 0.f}, o1 = o0, o2 = o0, o3 = o0;
  float lrun = 0.f;

  // prologue: stage tile 0 into buf 0
  gload16(kp0, &Ks[wbase]);
  gload16(kp1, &Ks[wbase + 512]);
  gload16(vp0, &Vs[wbase]);
  gload16(vp1, &Vs[wbase + 512]);
  kp0 += 4096; kp1 += 4096; vp0 += 64; vp1 += 64;
  __syncthreads();

  int cur = 0;
  for (int tile = 0; tile < 32; ++tile) {
    // ---- issue next tile's staging early (hides L2/HBM latency) ----
    if (tile != 31) {
      const int nb = (cur ^ 1) * 4096;
      gload16(kp0, &Ks[nb + wbase]);
      gload16(kp1, &Ks[nb + wbase + 512]);
      gload16(vp0, &Vs[nb + wbase]);
      gload16(vp1, &Vs[nb + wbase + 512]);
      kp0 += 4096; kp1 += 4096; vp0 += 64; vp1 += 64;
    }
    const int kb = cur * 4096;

    // ---- S^T = K . Q^T (rows = keys, cols = queries); s is exp2 arg ----
    f32x4 s0 = {0.f, 0.f, 0.f, 0.f}, s1 = s0, s2 = s0, s3 = s0;
#pragma unroll
    for (int kt = 0; kt < 2; ++kt) {
      const int dh0 = ((lg * 8 + 32 * kt) ^ sw) + kb;
      const bf16x8 qb = kt ? qf1 : qf0;
      s0 = __builtin_amdgcn_mfma_f32_16x16x32_bf16(
          *(const bf16x8*)&Ks[lq * 64 + dh0], qb, s0, 0, 0, 0);
      s1 = __builtin_amdgcn_mfma_f32_16x16x32_bf16(
          *(const bf16x8*)&Ks[(16 + lq) * 64 + dh0], qb, s1, 0, 0, 0);
      s2 = __builtin_amdgcn_mfma_f32_16x16x32_bf16(
          *(const bf16x8*)&Ks[(32 + lq) * 64 + dh0], qb, s2, 0, 0, 0);
      s3 = __builtin_amdgcn_mfma_f32_16x16x32_bf16(
          *(const bf16x8*)&Ks[(48 + lq) * 64 + dh0], qb, s3, 0, 0, 0);
    }

    // ---- P = 2^s -> bf16 LDS; accumulate l in registers ----
    float ls = 0.f;
#define PSTORE(SF, KF)                                                    \
    {                                                                     \
      float e0 = exp2f(SF[0]), e1 = exp2f(SF[1]);                         \
      float e2 = exp2f(SF[2]), e3 = exp2f(SF[3]);                         \
      ls += (e0 + e1) + (e2 + e3);                                        \
      uint2 pv;                                                           \
      pv.x = cvtpk(e0, e1);                                               \
      pv.y = cvtpk(e2, e3);                                               \
      *(uint2*)&Ps[qrow * 64 + ((16 * (KF) + 4 * lg) ^ sw)] = pv;         \
    }
    PSTORE(s0, 0) PSTORE(s1, 1) PSTORE(s2, 2) PSTORE(s3, 3)
#undef PSTORE
    lrun += ls;
    asm volatile("s_waitcnt lgkmcnt(0)" ::: "memory");
    __builtin_amdgcn_sched_barrier(0);

    // ---- O^T += V^T . P^T ----
#pragma unroll
    for (int kt = 0; kt < 2; ++kt) {
      const int k0 = (lg * 8 + 32 * kt) ^ sw;
      const bf16x8 pb = *(const bf16x8*)&Ps[qrow * 64 + k0];
      o0 = __builtin_amdgcn_mfma_f32_16x16x32_bf16(
          *(const bf16x8*)&Vs[lq * 64 + k0 + kb], pb, o0, 0, 0, 0);
      o1 = __builtin_amdgcn_mfma_f32_16x16x32_bf16(
          *(const bf16x8*)&Vs[(16 + lq) * 64 + k0 + kb], pb, o1, 0, 0, 0);
      o2 = __builtin_amdgcn_mfma_f32_16x16x32_bf16(
          *(const bf16x8*)&Vs[(32 + lq) * 64 + k0 + kb], pb, o2, 0, 0, 0);
      o3 = __builtin_amdgcn_mfma_f32_16x16x32_bf16(
          *(const bf16x8*)&Vs[(48 + lq) * 64 + k0 + kb], pb, o3, 0, 0, 0);
    }
    // one barrier per tile: drains this wave's gload_lds (vmcnt) + LDS ops,
    // then publishes buf^1 for the next iteration.
    __syncthreads();
    cur ^= 1;
  }

  // ---- finish l: sum across the 4 lg groups (keys 16sf+4lg+r) ----
  lrun += __shfl_xor(lrun, 16);
  lrun += __shfl_xor(lrun, 32);
  const float inv = 1.f / lrun;

  // ---- write msgT[b][n][h*64 + dh] bf16 (head-major; Wm cols permuted) ----
  ushort_t* mp = msgT + ((size_t)b * N_ + n00 + qrow) * 256 + h * 64;
  uint2 pv;
  pv = pack4(o0[0] * inv, o0[1] * inv, o0[2] * inv, o0[3] * inv);
  *(uint2*)&mp[0 + 4 * lg] = pv;
  pv = pack4(o1[0] * inv, o1[1] * inv, o1[2] * inv, o1[3] * inv);
  *(uint2*)&mp[16 + 4 * lg] = pv;
  pv = pack4(o2[0] * inv, o2[1] * inv, o2[2] * inv, o2[3] * inv);
  *(uint2*)&mp[32 + 4 * lg] = pv;
  pv = pack4(o3[0] * inv, o3[1] * inv, o3[2] * inv, o3[3] * inv);
  *(uint2*)&mp[48 + 4 * lg] = pv;
}

// ---------------------------------------------------------------------------
// 3) merge: msg2^T -> cat_t[:, 256:] (ld 512).  grid (16, 2, 8)
// ---------------------------------------------------------------------------
__global__ __launch_bounds__(256) void merge_mfma(
    const ushort_t* __restrict__ Wmb, const float* __restrict__ bm,
    const ushort_t* __restrict__ msgT, ushort_t* __restrict__ cat_t) {
  GEMM_PREAMBLE()
  const int b = blockIdx.z;
  const ushort_t* Arow = Wmb + (size_t)(m0 + lq) * 256;
  const ushort_t* Brow = msgT + ((size_t)b * N_ + n0 + lq) * 256;
  mfma_core<256, 256>(Arow, Brow, acc, lg);
  ushort_t* ob = cat_t + (size_t)b * N_ * 512 + 256;
#pragma unroll
  for (int fm = 0; fm < 4; ++fm) {
    const int o0 = m0 + 16 * fm + 4 * lg;
    float bb[4];
#pragma unroll
    for (int r = 0; r < 4; ++r) bb[r] = bm[o0 + r];
#pragma unroll
    for (int fn = 0; fn < 4; ++fn) {
      const int n = n0 + 16 * fn + lq;
      uint2 pv = pack4(acc[fm][fn][0] + bb[0], acc[fm][fn][1] + bb[1],
                       acc[fm][fn][2] + bb[2], acc[fm][fn][3] + bb[3]);
      *(uint2*)&ob[(size_t)n * 512 + o0] = pv;
    }
  }
}

// ---------------------------------------------------------------------------
// 4) W1: h1^T = (W1 @ cat)^T -> h1t[b][n][512] bf16.  grid (16, 4, 8)
// ---------------------------------------------------------------------------
__global__ __launch_bounds__(256) void w1_mfma(
    const ushort_t* __restrict__ W1b, const float* __restrict__ b1,
    const ushort_t* __restrict__ cat_t, ushort_t* __restrict__ h1t) {
  GEMM_PREAMBLE()
  const int b = blockIdx.z;
  const ushort_t* Arow = W1b + (size_t)(m0 + lq) * 512;
  const ushort_t* Brow = cat_t + ((size_t)b * N_ + n0 + lq) * 512;
  mfma_core<512, 512>(Arow, Brow, acc, lg);
  ushort_t* ob = h1t + (size_t)b * N_ * 512;
#pragma unroll
  for (int fm = 0; fm < 4; ++fm) {
    const int o0 = m0 + 16 * fm + 4 * lg;
    float bb[4];
#pragma unroll
    for (int r = 0; r < 4; ++r) bb[r] = b1[o0 + r];
#pragma unroll
    for (int fn = 0; fn < 4; ++fn) {
      const int n = n0 + 16 * fn + lq;
      uint2 pv = pack4(acc[fm][fn][0] + bb[0], acc[fm][fn][1] + bb[1],
                       acc[fm][fn][2] + bb[2], acc[fm][fn][3] + bb[3]);
      *(uint2*)&ob[(size_t)n * 512 + o0] = pv;
    }
  }
}

// ---------------------------------------------------------------------------
// 5) InstanceNorm stats on h1t
// ---------------------------------------------------------------------------
__global__ __launch_bounds__(256) void zero_stats(float* __restrict__ s) {
  s[blockIdx.x * 256 + threadIdx.x] = 0.f;  // grid 32 -> 8192 floats
}

// grid (8 nchunk, 8 cchunk, 8 b)
__global__ __launch_bounds__(256) void stats_partial(
    const ushort_t* __restrict__ h1t, float* __restrict__ ssum,
    float* __restrict__ ssq) {
  const int t = threadIdx.x;
  const int c = blockIdx.y * 64 + (t & 63);
  const int b = blockIdx.z;
  const int nbase = blockIdx.x * 256 + (t >> 6) * 64;
  const ushort_t* p = h1t + (size_t)b * N_ * 512;
  float s = 0.f, ss = 0.f;
  for (int i = 0; i < 64; ++i) {
    float v = bf2f(p[(size_t)(nbase + i) * 512 + c]);
    s += v; ss += v * v;
  }
  __shared__ float rs[4][64], rq[4][64];
  const int wv = t >> 6;
  rs[wv][t & 63] = s; rq[wv][t & 63] = ss;
  __syncthreads();
  if (t < 64) {
    float S = rs[0][t] + rs[1][t] + rs[2][t] + rs[3][t];
    float Q = rq[0][t] + rq[1][t] + rq[2][t] + rq[3][t];
    atomicAdd(&ssum[b * 512 + blockIdx.y * 64 + t], S);
    atomicAdd(&ssq[b * 512 + blockIdx.y * 64 + t], Q);
  }
}

__global__ __launch_bounds__(256) void finalize_stats(
    const float* __restrict__ ssum, const float* __restrict__ ssq,
    float* __restrict__ mean, float* __restrict__ istd) {
  const int i = blockIdx.x * 256 + threadIdx.x;  // grid 16 -> 4096
  float mn = ssum[i] * (1.f / N_);
  float var = ssq[i] * (1.f / N_) - mn * mn;
  mean[i] = mn;
  istd[i] = rsqrtf(var + 1e-5f);
}

// ---------------------------------------------------------------------------
// 6) normalize+relu: h1n = relu((h1t - mean) * istd) bf16.  grid 4096
// ---------------------------------------------------------------------------
__global__ __launch_bounds__(256) void normalize_h1(
    const ushort_t* __restrict__ h1t, const float* __restrict__ mean,
    const float* __restrict__ istd, ushort_t* __restrict__ h1n) {
  const size_t ci = (size_t)blockIdx.x * 256 + threadIdx.x;
  const size_t basei = ci * 8;
  const int c0 = (int)(basei & 511);
  const size_t row = basei >> 9;  // b*N + n
  const int b = (int)(row >> 11);
  const float* mp = mean + b * 512 + c0;
  const float* ip = istd + b * 512 + c0;
  union { bf16x8 v; ushort_t u[8]; } in;
  in.v = *(const bf16x8*)&h1t[basei];
  float g[8];
#pragma unroll
  for (int j = 0; j < 8; ++j)
    g[j] = fmaxf((bf2f(in.u[j]) - mp[j]) * ip[j], 0.f);
  uint4 pv;
  pv.x = cvtpk(g[0], g[1]);
  pv.y = cvtpk(g[2], g[3]);
  pv.z = cvtpk(g[4], g[5]);
  pv.w = cvtpk(g[6], g[7]);
  *(uint4*)&h1n[basei] = pv;
}

// ---------------------------------------------------------------------------
// 7) W2: out = W2 @ h1n + b2, f32 [b][256][N].  grid (16, 2, 8)
// ---------------------------------------------------------------------------
__global__ __launch_bounds__(256) void w2_mfma(
    const ushort_t* __restrict__ W2b, const float* __restrict__ b2,
    const ushort_t* __restrict__ h1n, float* __restrict__ out) {
  GEMM_PREAMBLE()
  const int b = blockIdx.z;
  const ushort_t* Arow = W2b + (size_t)(m0 + lq) * 512;
  const ushort_t* Brow = h1n + ((size_t)b * N_ + n0 + lq) * 512;
  mfma_core<512, 512>(Arow, Brow, acc, lg);
  float* ob = out + (size_t)b * D_ * N_;
#pragma unroll
  for (int fm = 0; fm < 4; ++fm) {
    const int o0 = m0 + 16 * fm + 4 * lg;
    float bb[4];
#pragma unroll
    for (int r = 0; r < 4; ++r) bb[r] = b2[o0 + r];
#pragma unroll
    for (int fn = 0; fn < 4; ++fn) {
      const int n = n0 + 16 * fn + lq;
#pragma unroll
      for (int r = 0; r < 4; ++r)
        ob[(size_t)(o0 + r) * N_ + n] = acc[fm][fn][r] + bb[r];
    }
  }
}

// ---------------------------------------------------------------------------
extern "C" void kernel_launch(void* const* d_in, const int* in_sizes, int n_in,
                              void* d_out, int out_size, void* d_ws,
                              size_t ws_size, hipStream_t stream) {
  const float* x = (const float*)d_in[0];
  const float* source = (const float*)d_in[1];
  const float* Wq = (const float*)d_in[2];
  const float* bq = (const float*)d_in[3];
  const float* Wk = (const float*)d_in[4];
  const float* bk = (const float*)d_in[5];
  const float* Wv = (const float*)d_in[6];
  const float* bv = (const float*)d_in[7];
  const float* Wm = (const float*)d_in[8];
  const float* bm = (const float*)d_in[9];
  const float* W1 = (const float*)d_in[10];
  const float* b1 = (const float*)d_in[11];
  const float* W2 = (const float*)d_in[12];
  const float* b2 = (const float*)d_in[13];
  float* out = (float*)d_out;

  char* w = (char*)d_ws;
  size_t off = 0;
  auto alloc = [&](size_t bytes) {
    void* p = w + off;
    off = (off + bytes + 255) & ~(size_t)255;
    return p;
  };
  ushort_t* cat_t = (ushort_t*)alloc((size_t)B_ * N_ * 512 * 2);  // x^T | msg2^T
  ushort_t* st    = (ushort_t*)alloc((size_t)B_ * N_ * 256 * 2);
  ushort_t* Qt    = (ushort_t*)alloc((size_t)B_ * 4 * N_ * 64 * 2);
  ushort_t* Kt    = (ushort_t*)alloc((size_t)B_ * 4 * N_ * 64 * 2);
  ushort_t* Vt    = (ushort_t*)alloc((size_t)B_ * 256 * N_ * 2);
  ushort_t* msgT  = (ushort_t*)alloc((size_t)B_ * N_ * 256 * 2);
  ushort_t* h1t   = (ushort_t*)alloc((size_t)B_ * N_ * 512 * 2);
  ushort_t* h1n   = (ushort_t*)alloc((size_t)B_ * N_ * 512 * 2);
  float* ssum = (float*)alloc(4096 * 4);
  float* ssq  = (float*)alloc(4096 * 4);
  float* mean = (float*)alloc(4096 * 4);
  float* istd = (float*)alloc(4096 * 4);
  ushort_t* Wqb = (ushort_t*)alloc(65536 * 2);
  ushort_t* Wkb = (ushort_t*)alloc(65536 * 2);
  ushort_t* Wvb = (ushort_t*)alloc(65536 * 2);
  ushort_t* Wmb = (ushort_t*)alloc(65536 * 2);
  ushort_t* W1b = (ushort_t*)alloc(262144 * 2);
  ushort_t* W2b = (ushort_t*)alloc(131072 * 2);

  prep_weights<<<2560, 256, 0, stream>>>(Wq, Wk, Wv, Wm, W1, W2, Wqb, Wkb,
                                         Wvb, Wmb, W1b, W2b);
  transpose_in<<<dim3(32, 4, 16), 256, 0, stream>>>(x, source, cat_t, st);
  zero_stats<<<32, 256, 0, stream>>>(ssum);  // ssum+ssq contiguous (8192 f32)
  q_mfma<<<dim3(16, 2, 8), 256, 0, stream>>>(Wqb, bq, cat_t, Qt);
  kv_mfma<<<dim3(16, 2, 16), 256, 0, stream>>>(Wkb, Wvb, bk, bv, st, Kt, Vt);
  attn_mfma<<<dim3(1024), 256, 0, stream>>>(Qt, Kt, Vt, msgT);
  merge_mfma<<<dim3(16, 2, 8), 256, 0, stream>>>(Wmb, bm, msgT, cat_t);
  w1_mfma<<<dim3(16, 4, 8), 256, 0, stream>>>(W1b, b1, cat_t, h1t);
  stats_partial<<<dim3(8, 8, 8), 256, 0, stream>>>(h1t, ssum, ssq);
  finalize_stats<<<16, 256, 0, stream>>>(ssum, ssq, mean, istd);
  normalize_h1<<<4096, 256, 0, stream>>>(h1t, mean, istd, h1n);
  w2_mfma<<<dim3(16, 2, 8), 256, 0, stream>>>(W2b, b2, h1n, out);
}

// Round 9
// 285.016 us; speedup vs baseline: 1.0547x; 1.0065x over previous
//
#include <hip/hip_runtime.h>
#include <hip/hip_bf16.h>

// Problem constants
#define B_  8
#define D_  256
#define N_  2048
#define M_  2048
#define H_  4
#define DH_ 64
#define D2_ 512

// 0.125 (1/sqrt(DH)) * log2(e), folded into Wq/bq so QK^T MFMA output is
// directly the exp2 argument.
#define SCL_QK 0.1803368801f

typedef unsigned short ushort_t;
typedef __attribute__((ext_vector_type(8))) short bf16x8;
typedef __attribute__((ext_vector_type(4))) short bf16x4;
typedef __attribute__((ext_vector_type(4))) float f32x4;

// Packed f32->bf16 RNE conversion (no builtin on gfx950 - T12 recipe).
__device__ __forceinline__ unsigned cvtpk(float a, float b) {
  unsigned r;
  asm("v_cvt_pk_bf16_f32 %0, %1, %2" : "=v"(r) : "v"(a), "v"(b));
  return r;
}
__device__ __forceinline__ ushort_t f2bf1(float x) {
  return (ushort_t)cvtpk(x, x);
}
__device__ __forceinline__ float bf2f(ushort_t h) {
  union { unsigned u; float f; } c; c.u = ((unsigned)h) << 16; return c.f;
}
__device__ __forceinline__ uint2 pack4(float a, float b, float c, float d) {
  uint2 r; r.x = cvtpk(a, b); r.y = cvtpk(c, d); return r;
}

// Async global->LDS, 16B per lane. LDS dest = wave-uniform base + lane*16.
__device__ __forceinline__ void gload16(const ushort_t* g, ushort_t* l) {
  __builtin_amdgcn_global_load_lds(
      (const __attribute__((address_space(1))) unsigned*)g,
      (__attribute__((address_space(3))) unsigned*)l, 16, 0, 0);
}

// ---------------------------------------------------------------------------
// MFMA GEMM core: 128x128 tile, 4 waves (2x2), per-wave 64x64 (4x4 frags).
// A bf16 [O][K] row-major; Bt bf16 [N][LDB] (k fastest). No LDS: fragments
// stream straight from global (operands are L2-resident).
// D[o][n]: o = m0 + 16*fm + 4*lg + r, n = n0 + 16*fn + lq.
// ---------------------------------------------------------------------------
template <int K, int LDB>
__device__ __forceinline__ void mfma_core(const ushort_t* __restrict__ Arow,
                                          const ushort_t* __restrict__ Brow,
                                          f32x4 acc[4][4], int lg) {
#pragma unroll 2
  for (int k0 = 0; k0 < K; k0 += 32) {
    bf16x8 af[4], bfr[4];
#pragma unroll
    for (int f = 0; f < 4; ++f)
      af[f] = *(const bf16x8*)&Arow[(size_t)16 * f * K + k0 + lg * 8];
#pragma unroll
    for (int f = 0; f < 4; ++f)
      bfr[f] = *(const bf16x8*)&Brow[(size_t)16 * f * LDB + k0 + lg * 8];
#pragma unroll
    for (int fm = 0; fm < 4; ++fm)
#pragma unroll
      for (int fn = 0; fn < 4; ++fn)
        acc[fm][fn] = __builtin_amdgcn_mfma_f32_16x16x32_bf16(
            af[fm], bfr[fn], acc[fm][fn], 0, 0, 0);
  }
}

#define GEMM_PREAMBLE()                                   \
  const int t = threadIdx.x, lane = t & 63, wv = t >> 6;  \
  const int wm = wv >> 1, wn = wv & 1;                    \
  const int lq = lane & 15, lg = lane >> 4;               \
  const int m0 = blockIdx.y * 128 + wm * 64;              \
  const int n0 = blockIdx.x * 128 + wn * 64;              \
  f32x4 acc[4][4];                                        \
  _Pragma("unroll") for (int i = 0; i < 4; ++i)           \
  _Pragma("unroll") for (int j = 0; j < 4; ++j)           \
      acc[i][j] = (f32x4){0.f, 0.f, 0.f, 0.f};

// ---------------------------------------------------------------------------
// 0) prep: weights -> bf16 (Wq pre-scaled; Wm column-permuted head-major)
//    + zero the stats accumulators (ssum|ssq contiguous, 8192 floats).
// grid: 2592 x 256
// ---------------------------------------------------------------------------
__global__ __launch_bounds__(256) void prep_kernel(
    const float* __restrict__ Wq, const float* __restrict__ Wk,
    const float* __restrict__ Wv, const float* __restrict__ Wm,
    const float* __restrict__ W1, const float* __restrict__ W2,
    ushort_t* __restrict__ Wqb, ushort_t* __restrict__ Wkb,
    ushort_t* __restrict__ Wvb, ushort_t* __restrict__ Wmb,
    ushort_t* __restrict__ W1b, ushort_t* __restrict__ W2b,
    float* __restrict__ stats) {
  const int idx = blockIdx.x * 256 + threadIdx.x;
  if (idx < 65536) {
    Wqb[idx] = f2bf1(Wq[idx] * SCL_QK);
  } else if (idx < 131072) {
    int j = idx - 65536; Wkb[j] = f2bf1(Wk[j]);
  } else if (idx < 196608) {
    int j = idx - 131072; Wvb[j] = f2bf1(Wv[j]);
  } else if (idx < 262144) {
    int j = idx - 196608;
    int e = j >> 8, cp = j & 255;
    int h = cp >> 6, dh = cp & 63;
    Wmb[j] = f2bf1(Wm[e * 256 + dh * 4 + h]);
  } else if (idx < 524288) {
    int j = idx - 262144; W1b[j] = f2bf1(W1[j]);
  } else if (idx < 655360) {
    int j = idx - 524288; W2b[j] = f2bf1(W2[j]);
  } else {
    int j = idx - 655360;  // 8192 floats: ssum (4096) | ssq (4096)
    if (j < 8192) stats[j] = 0.f;
  }
}

// ---------------------------------------------------------------------------
// 0.5) Transpose x -> cat_t[:, :256] (ld 512) and source -> st (ld 256), bf16.
// grid: (32, 4, 16) ; z: b = z&7, which = z>>3
// ---------------------------------------------------------------------------
__global__ __launch_bounds__(256) void transpose_in(
    const float* __restrict__ x, const float* __restrict__ source,
    ushort_t* __restrict__ cat_t, ushort_t* __restrict__ st) {
  __shared__ float T[64][65];
  const int t = threadIdx.x;
  const int b = blockIdx.z & 7, which = blockIdx.z >> 3;
  const float* sb = (which ? source : x) + (size_t)b * D_ * N_;
  ushort_t* dst = which ? st + (size_t)b * N_ * 256 : cat_t + (size_t)b * N_ * 512;
  const int ldc = which ? 256 : 512;
  const int d0 = blockIdx.y * 64, n0 = blockIdx.x * 64;
  const int nn = t & 63, dd = t >> 6;
#pragma unroll
  for (int p = 0; p < 16; ++p)
    T[dd + 4 * p][nn] = sb[(size_t)(d0 + dd + 4 * p) * N_ + n0 + nn];
  __syncthreads();
  const int dg = t & 7, nr = t >> 3;
#pragma unroll
  for (int p = 0; p < 2; ++p) {
    int n = nr + 32 * p;
    uint4 pv;
    pv.x = cvtpk(T[dg * 8 + 0][n], T[dg * 8 + 1][n]);
    pv.y = cvtpk(T[dg * 8 + 2][n], T[dg * 8 + 3][n]);
    pv.z = cvtpk(T[dg * 8 + 4][n], T[dg * 8 + 5][n]);
    pv.w = cvtpk(T[dg * 8 + 6][n], T[dg * 8 + 7][n]);
    *(uint4*)&dst[(size_t)(n0 + n) * ldc + d0 + dg * 8] = pv;
  }
}

// ---------------------------------------------------------------------------
// 1) Fused QKV projections. z: b = z/3, w = z%3 (0=Q from x, 1=K, 2=V).
//    Q/K -> [bh][n][64] bf16 (Q pre-scaled); V -> [bh][dh][m] bf16.
// grid (16, 2, 24)
// ---------------------------------------------------------------------------
__global__ __launch_bounds__(256) void qkv_mfma(
    const ushort_t* __restrict__ Wqb, const ushort_t* __restrict__ Wkb,
    const ushort_t* __restrict__ Wvb, const float* __restrict__ bq,
    const float* __restrict__ bk, const float* __restrict__ bv,
    const ushort_t* __restrict__ cat_t, const ushort_t* __restrict__ st,
    ushort_t* __restrict__ Qt, ushort_t* __restrict__ Kt,
    ushort_t* __restrict__ Vt) {
  const int z = blockIdx.z;
  const int b = z / 3, w = z % 3;
  GEMM_PREAMBLE()
  if (w == 0) {
    const ushort_t* Arow = Wqb + (size_t)(m0 + lq) * 256;
    const ushort_t* Brow = cat_t + ((size_t)b * N_ + n0 + lq) * 512;
    mfma_core<256, 512>(Arow, Brow, acc, lg);
    ushort_t* Qb = Qt + (size_t)b * 4 * N_ * 64;
#pragma unroll
    for (int fm = 0; fm < 4; ++fm) {
      const int o0 = m0 + 16 * fm + 4 * lg;
      const int hh = o0 >> 6, dl = o0 & 63;
      float bb[4];
#pragma unroll
      for (int r = 0; r < 4; ++r) bb[r] = bq[o0 + r] * SCL_QK;
#pragma unroll
      for (int fn = 0; fn < 4; ++fn) {
        const int n = n0 + 16 * fn + lq;
        uint2 pv = pack4(acc[fm][fn][0] + bb[0], acc[fm][fn][1] + bb[1],
                         acc[fm][fn][2] + bb[2], acc[fm][fn][3] + bb[3]);
        *(uint2*)&Qb[((size_t)hh * N_ + n) * 64 + dl] = pv;
      }
    }
  } else if (w == 1) {
    const ushort_t* Arow = Wkb + (size_t)(m0 + lq) * 256;
    const ushort_t* Brow = st + ((size_t)b * N_ + n0 + lq) * 256;
    mfma_core<256, 256>(Arow, Brow, acc, lg);
    ushort_t* Kb = Kt + (size_t)b * 4 * N_ * 64;
#pragma unroll
    for (int fm = 0; fm < 4; ++fm) {
      const int o0 = m0 + 16 * fm + 4 * lg;
      const int hh = o0 >> 6, dl = o0 & 63;
      float bb[4];
#pragma unroll
      for (int r = 0; r < 4; ++r) bb[r] = bk[o0 + r];
#pragma unroll
      for (int fn = 0; fn < 4; ++fn) {
        const int n = n0 + 16 * fn + lq;
        uint2 pv = pack4(acc[fm][fn][0] + bb[0], acc[fm][fn][1] + bb[1],
                         acc[fm][fn][2] + bb[2], acc[fm][fn][3] + bb[3]);
        *(uint2*)&Kb[((size_t)hh * N_ + n) * 64 + dl] = pv;
      }
    }
  } else {
    const ushort_t* Arow = Wvb + (size_t)(m0 + lq) * 256;
    const ushort_t* Brow = st + ((size_t)b * N_ + n0 + lq) * 256;
    mfma_core<256, 256>(Arow, Brow, acc, lg);
    ushort_t* Vb = Vt + (size_t)b * 256 * N_;
#pragma unroll
    for (int fm = 0; fm < 4; ++fm) {
      const int o0 = m0 + 16 * fm + 4 * lg;
      float bb[4];
#pragma unroll
      for (int r = 0; r < 4; ++r) bb[r] = bv[o0 + r];
#pragma unroll
      for (int fn = 0; fn < 4; ++fn) {
        const int n = n0 + 16 * fn + lq;
#pragma unroll
        for (int r = 0; r < 4; ++r)
          Vb[(size_t)(o0 + r) * N_ + n] = f2bf1(acc[fm][fn][r] + bb[r]);
      }
    }
  }
}

// ---------------------------------------------------------------------------
// 2) MFMA flash attention (byte-identical to R8): max-free softmax,
//    gload_lds dbuf K/V, one barrier/tile, in-register l-sum.
// grid: 1024 (XCD-swizzled), 256 threads
// ---------------------------------------------------------------------------
__global__ __launch_bounds__(256) void attn_mfma(
    const ushort_t* __restrict__ Qt, const ushort_t* __restrict__ Kt,
    const ushort_t* __restrict__ Vt, ushort_t* __restrict__ msgT) {
  __shared__ __align__(16) ushort_t Ks[2 * 64 * 64];  // [buf][key][dh] swz
  __shared__ __align__(16) ushort_t Vs[2 * 64 * 64];  // [buf][dh][key] swz
  __shared__ __align__(16) ushort_t Ps[64 * 64];      // [q][key] swz (wave-priv)
  const int t = threadIdx.x;
  const int lane = t & 63, wq = t >> 6;
  const int flat = blockIdx.x;
  const int logical = (flat & 7) * 128 + (flat >> 3);
  const int qt = logical & 31, h = (logical >> 5) & 3, b = logical >> 7;
  const int bh = b * H_ + h;
  const size_t base = (size_t)bh * 64 * N_;
  const int n00 = qt * 64;
  const int lq = lane & 15, lg = lane >> 4;
  const int qrow = wq * 16 + lq;
  const int sw = (lq & 7) * 8;

  const int r0 = wq * 16 + (lane >> 3);
  const int r1 = r0 + 8;
  const int c8 = lane & 7;
  const ushort_t* kp0 = Kt + base + (size_t)r0 * 64 + ((c8 ^ (r0 & 7)) * 8);
  const ushort_t* kp1 = Kt + base + (size_t)r1 * 64 + ((c8 ^ (r1 & 7)) * 8);
  const ushort_t* vp0 = Vt + base + (size_t)r0 * N_ + ((c8 ^ (r0 & 7)) * 8);
  const ushort_t* vp1 = Vt + base + (size_t)r1 * N_ + ((c8 ^ (r1 & 7)) * 8);
  const int wbase = wq * 1024;

  bf16x8 qf0, qf1;
  {
    const ushort_t* qp = Qt + base + (size_t)(n00 + qrow) * 64 + lg * 8;
    qf0 = *(const bf16x8*)qp;
    qf1 = *(const bf16x8*)(qp + 32);
  }
  f32x4 o0 = {0.f, 0.f, 0.f, 0.f}, o1 = o0, o2 = o0, o3 = o0;
  float lrun = 0.f;

  gload16(kp0, &Ks[wbase]);
  gload16(kp1, &Ks[wbase + 512]);
  gload16(vp0, &Vs[wbase]);
  gload16(vp1, &Vs[wbase + 512]);
  kp0 += 4096; kp1 += 4096; vp0 += 64; vp1 += 64;
  __syncthreads();

  int cur = 0;
  for (int tile = 0; tile < 32; ++tile) {
    if (tile != 31) {
      const int nb = (cur ^ 1) * 4096;
      gload16(kp0, &Ks[nb + wbase]);
      gload16(kp1, &Ks[nb + wbase + 512]);
      gload16(vp0, &Vs[nb + wbase]);
      gload16(vp1, &Vs[nb + wbase + 512]);
      kp0 += 4096; kp1 += 4096; vp0 += 64; vp1 += 64;
    }
    const int kb = cur * 4096;

    f32x4 s0 = {0.f, 0.f, 0.f, 0.f}, s1 = s0, s2 = s0, s3 = s0;
#pragma unroll
    for (int kt = 0; kt < 2; ++kt) {
      const int dh0 = ((lg * 8 + 32 * kt) ^ sw) + kb;
      const bf16x8 qb = kt ? qf1 : qf0;
      s0 = __builtin_amdgcn_mfma_f32_16x16x32_bf16(
          *(const bf16x8*)&Ks[lq * 64 + dh0], qb, s0, 0, 0, 0);
      s1 = __builtin_amdgcn_mfma_f32_16x16x32_bf16(
          *(const bf16x8*)&Ks[(16 + lq) * 64 + dh0], qb, s1, 0, 0, 0);
      s2 = __builtin_amdgcn_mfma_f32_16x16x32_bf16(
          *(const bf16x8*)&Ks[(32 + lq) * 64 + dh0], qb, s2, 0, 0, 0);
      s3 = __builtin_amdgcn_mfma_f32_16x16x32_bf16(
          *(const bf16x8*)&Ks[(48 + lq) * 64 + dh0], qb, s3, 0, 0, 0);
    }

    float ls = 0.f;
#define PSTORE(SF, KF)                                                    \
    {                                                                     \
      float e0 = exp2f(SF[0]), e1 = exp2f(SF[1]);                         \
      float e2 = exp2f(SF[2]), e3 = exp2f(SF[3]);                         \
      ls += (e0 + e1) + (e2 + e3);                                        \
      uint2 pv;                                                           \
      pv.x = cvtpk(e0, e1);                                               \
      pv.y = cvtpk(e2, e3);                                               \
      *(uint2*)&Ps[qrow * 64 + ((16 * (KF) + 4 * lg) ^ sw)] = pv;         \
    }
    PSTORE(s0, 0) PSTORE(s1, 1) PSTORE(s2, 2) PSTORE(s3, 3)
#undef PSTORE
    lrun += ls;
    asm volatile("s_waitcnt lgkmcnt(0)" ::: "memory");
    __builtin_amdgcn_sched_barrier(0);

#pragma unroll
    for (int kt = 0; kt < 2; ++kt) {
      const int k0 = (lg * 8 + 32 * kt) ^ sw;
      const bf16x8 pb = *(const bf16x8*)&Ps[qrow * 64 + k0];
      o0 = __builtin_amdgcn_mfma_f32_16x16x32_bf16(
          *(const bf16x8*)&Vs[lq * 64 + k0 + kb], pb, o0, 0, 0, 0);
      o1 = __builtin_amdgcn_mfma_f32_16x16x32_bf16(
          *(const bf16x8*)&Vs[(16 + lq) * 64 + k0 + kb], pb, o1, 0, 0, 0);
      o2 = __builtin_amdgcn_mfma_f32_16x16x32_bf16(
          *(const bf16x8*)&Vs[(32 + lq) * 64 + k0 + kb], pb, o2, 0, 0, 0);
      o3 = __builtin_amdgcn_mfma_f32_16x16x32_bf16(
          *(const bf16x8*)&Vs[(48 + lq) * 64 + k0 + kb], pb, o3, 0, 0, 0);
    }
    __syncthreads();
    cur ^= 1;
  }

  lrun += __shfl_xor(lrun, 16);
  lrun += __shfl_xor(lrun, 32);
  const float inv = 1.f / lrun;

  ushort_t* mp = msgT + ((size_t)b * N_ + n00 + qrow) * 256 + h * 64;
  uint2 pv;
  pv = pack4(o0[0] * inv, o0[1] * inv, o0[2] * inv, o0[3] * inv);
  *(uint2*)&mp[0 + 4 * lg] = pv;
  pv = pack4(o1[0] * inv, o1[1] * inv, o1[2] * inv, o1[3] * inv);
  *(uint2*)&mp[16 + 4 * lg] = pv;
  pv = pack4(o2[0] * inv, o2[1] * inv, o2[2] * inv, o2[3] * inv);
  *(uint2*)&mp[32 + 4 * lg] = pv;
  pv = pack4(o3[0] * inv, o3[1] * inv, o3[2] * inv, o3[3] * inv);
  *(uint2*)&mp[48 + 4 * lg] = pv;
}

// ---------------------------------------------------------------------------
// 3) merge: msg2^T -> cat_t[:, 256:] (ld 512).  grid (16, 2, 8)
// ---------------------------------------------------------------------------
__global__ __launch_bounds__(256) void merge_mfma(
    const ushort_t* __restrict__ Wmb, const float* __restrict__ bm,
    const ushort_t* __restrict__ msgT, ushort_t* __restrict__ cat_t) {
  GEMM_PREAMBLE()
  const int b = blockIdx.z;
  const ushort_t* Arow = Wmb + (size_t)(m0 + lq) * 256;
  const ushort_t* Brow = msgT + ((size_t)b * N_ + n0 + lq) * 256;
  mfma_core<256, 256>(Arow, Brow, acc, lg);
  ushort_t* ob = cat_t + (size_t)b * N_ * 512 + 256;
#pragma unroll
  for (int fm = 0; fm < 4; ++fm) {
    const int o0 = m0 + 16 * fm + 4 * lg;
    float bb[4];
#pragma unroll
    for (int r = 0; r < 4; ++r) bb[r] = bm[o0 + r];
#pragma unroll
    for (int fn = 0; fn < 4; ++fn) {
      const int n = n0 + 16 * fn + lq;
      uint2 pv = pack4(acc[fm][fn][0] + bb[0], acc[fm][fn][1] + bb[1],
                       acc[fm][fn][2] + bb[2], acc[fm][fn][3] + bb[3]);
      *(uint2*)&ob[(size_t)n * 512 + o0] = pv;
    }
  }
}

// ---------------------------------------------------------------------------
// 4) W1 + fused InstanceNorm partial stats. h1^T -> h1t[b][n][512] bf16;
//    per-block row partials (sum, sumsq over this block's 128 n) reduced
//    in-register (shfl over lq) then atomicAdd into ssum/ssq.
// grid (16, 4, 8)
// ---------------------------------------------------------------------------
__global__ __launch_bounds__(256) void w1_mfma(
    const ushort_t* __restrict__ W1b, const float* __restrict__ b1,
    const ushort_t* __restrict__ cat_t, ushort_t* __restrict__ h1t,
    float* __restrict__ ssum, float* __restrict__ ssq) {
  GEMM_PREAMBLE()
  const int b = blockIdx.z;
  const ushort_t* Arow = W1b + (size_t)(m0 + lq) * 512;
  const ushort_t* Brow = cat_t + ((size_t)b * N_ + n0 + lq) * 512;
  mfma_core<512, 512>(Arow, Brow, acc, lg);
  ushort_t* ob = h1t + (size_t)b * N_ * 512;
  // bias into acc, write h1t
#pragma unroll
  for (int fm = 0; fm < 4; ++fm) {
    const int o0 = m0 + 16 * fm + 4 * lg;
    float bb[4];
#pragma unroll
    for (int r = 0; r < 4; ++r) bb[r] = b1[o0 + r];
#pragma unroll
    for (int fn = 0; fn < 4; ++fn) {
#pragma unroll
      for (int r = 0; r < 4; ++r) acc[fm][fn][r] += bb[r];
      const int n = n0 + 16 * fn + lq;
      uint2 pv = pack4(acc[fm][fn][0], acc[fm][fn][1], acc[fm][fn][2],
                       acc[fm][fn][3]);
      *(uint2*)&ob[(size_t)n * 512 + o0] = pv;
    }
  }
  // partial stats: per (fm, r) sum over fn (4 n's) then over lq (16 lanes)
#pragma unroll
  for (int fm = 0; fm < 4; ++fm) {
#pragma unroll
    for (int r = 0; r < 4; ++r) {
      float sv = 0.f, qv = 0.f;
#pragma unroll
      for (int fn = 0; fn < 4; ++fn) {
        float v = acc[fm][fn][r];
        sv += v;
        qv += v * v;
      }
#pragma unroll
      for (int off = 1; off < 16; off <<= 1) {
        sv += __shfl_xor(sv, off);
        qv += __shfl_xor(qv, off);
      }
      if (lq == 0) {
        const int o = m0 + 16 * fm + 4 * lg + r;
        atomicAdd(&ssum[b * 512 + o], sv);
        atomicAdd(&ssq[b * 512 + o], qv);
      }
    }
  }
}

// ---------------------------------------------------------------------------
// 5) normalize+relu with inline finalize: h1n = relu((h1t - mean)*istd).
//    mean/istd computed from ssum/ssq on the fly (stats are L1-resident).
// grid 4096
// ---------------------------------------------------------------------------
__global__ __launch_bounds__(256) void normalize_h1(
    const ushort_t* __restrict__ h1t, const float* __restrict__ ssum,
    const float* __restrict__ ssq, ushort_t* __restrict__ h1n) {
  const size_t ci = (size_t)blockIdx.x * 256 + threadIdx.x;
  const size_t basei = ci * 8;
  const int c0 = (int)(basei & 511);
  const size_t row = basei >> 9;  // b*N + n
  const int b = (int)(row >> 11);
  const float* sp = ssum + b * 512 + c0;
  const float* qp = ssq + b * 512 + c0;
  union { bf16x8 v; ushort_t u[8]; } in;
  in.v = *(const bf16x8*)&h1t[basei];
  float g[8];
#pragma unroll
  for (int j = 0; j < 8; ++j) {
    float mn = sp[j] * (1.f / N_);
    float var = qp[j] * (1.f / N_) - mn * mn;
    float istd = rsqrtf(var + 1e-5f);
    g[j] = fmaxf((bf2f(in.u[j]) - mn) * istd, 0.f);
  }
  uint4 pv;
  pv.x = cvtpk(g[0], g[1]);
  pv.y = cvtpk(g[2], g[3]);
  pv.z = cvtpk(g[4], g[5]);
  pv.w = cvtpk(g[6], g[7]);
  *(uint4*)&h1n[basei] = pv;
}

// ---------------------------------------------------------------------------
// 6) W2: out = W2 @ h1n + b2, f32 [b][256][N].  grid (16, 2, 8)
// ---------------------------------------------------------------------------
__global__ __launch_bounds__(256) void w2_mfma(
    const ushort_t* __restrict__ W2b, const float* __restrict__ b2,
    const ushort_t* __restrict__ h1n, float* __restrict__ out) {
  GEMM_PREAMBLE()
  const int b = blockIdx.z;
  const ushort_t* Arow = W2b + (size_t)(m0 + lq) * 512;
  const ushort_t* Brow = h1n + ((size_t)b * N_ + n0 + lq) * 512;
  mfma_core<512, 512>(Arow, Brow, acc, lg);
  float* ob = out + (size_t)b * D_ * N_;
#pragma unroll
  for (int fm = 0; fm < 4; ++fm) {
    const int o0 = m0 + 16 * fm + 4 * lg;
    float bb[4];
#pragma unroll
    for (int r = 0; r < 4; ++r) bb[r] = b2[o0 + r];
#pragma unroll
    for (int fn = 0; fn < 4; ++fn) {
      const int n = n0 + 16 * fn + lq;
#pragma unroll
      for (int r = 0; r < 4; ++r)
        ob[(size_t)(o0 + r) * N_ + n] = acc[fm][fn][r] + bb[r];
    }
  }
}

// ---------------------------------------------------------------------------
extern "C" void kernel_launch(void* const* d_in, const int* in_sizes, int n_in,
                              void* d_out, int out_size, void* d_ws,
                              size_t ws_size, hipStream_t stream) {
  const float* x = (const float*)d_in[0];
  const float* source = (const float*)d_in[1];
  const float* Wq = (const float*)d_in[2];
  const float* bq = (const float*)d_in[3];
  const float* Wk = (const float*)d_in[4];
  const float* bk = (const float*)d_in[5];
  const float* Wv = (const float*)d_in[6];
  const float* bv = (const float*)d_in[7];
  const float* Wm = (const float*)d_in[8];
  const float* bm = (const float*)d_in[9];
  const float* W1 = (const float*)d_in[10];
  const float* b1 = (const float*)d_in[11];
  const float* W2 = (const float*)d_in[12];
  const float* b2 = (const float*)d_in[13];
  float* out = (float*)d_out;

  char* w = (char*)d_ws;
  size_t off = 0;
  auto alloc = [&](size_t bytes) {
    void* p = w + off;
    off = (off + bytes + 255) & ~(size_t)255;
    return p;
  };
  ushort_t* cat_t = (ushort_t*)alloc((size_t)B_ * N_ * 512 * 2);  // x^T | msg2^T
  ushort_t* st    = (ushort_t*)alloc((size_t)B_ * N_ * 256 * 2);
  ushort_t* Qt    = (ushort_t*)alloc((size_t)B_ * 4 * N_ * 64 * 2);
  ushort_t* Kt    = (ushort_t*)alloc((size_t)B_ * 4 * N_ * 64 * 2);
  ushort_t* Vt    = (ushort_t*)alloc((size_t)B_ * 256 * N_ * 2);
  ushort_t* msgT  = (ushort_t*)alloc((size_t)B_ * N_ * 256 * 2);
  ushort_t* h1t   = (ushort_t*)alloc((size_t)B_ * N_ * 512 * 2);
  ushort_t* h1n   = (ushort_t*)alloc((size_t)B_ * N_ * 512 * 2);
  float* ssum = (float*)alloc(4096 * 4);  // contiguous with ssq (16KB, 256-aligned)
  float* ssq  = (float*)alloc(4096 * 4);
  ushort_t* Wqb = (ushort_t*)alloc(65536 * 2);
  ushort_t* Wkb = (ushort_t*)alloc(65536 * 2);
  ushort_t* Wvb = (ushort_t*)alloc(65536 * 2);
  ushort_t* Wmb = (ushort_t*)alloc(65536 * 2);
  ushort_t* W1b = (ushort_t*)alloc(262144 * 2);
  ushort_t* W2b = (ushort_t*)alloc(131072 * 2);

  prep_kernel<<<2592, 256, 0, stream>>>(Wq, Wk, Wv, Wm, W1, W2, Wqb, Wkb, Wvb,
                                        Wmb, W1b, W2b, ssum);
  transpose_in<<<dim3(32, 4, 16), 256, 0, stream>>>(x, source, cat_t, st);
  qkv_mfma<<<dim3(16, 2, 24), 256, 0, stream>>>(Wqb, Wkb, Wvb, bq, bk, bv,
                                                cat_t, st, Qt, Kt, Vt);
  attn_mfma<<<dim3(1024), 256, 0, stream>>>(Qt, Kt, Vt, msgT);
  merge_mfma<<<dim3(16, 2, 8), 256, 0, stream>>>(Wmb, bm, msgT, cat_t);
  w1_mfma<<<dim3(16, 4, 8), 256, 0, stream>>>(W1b, b1, cat_t, h1t, ssum, ssq);
  normalize_h1<<<4096, 256, 0, stream>>>(h1t, ssum, ssq, h1n);
  w2_mfma<<<dim3(16, 2, 8), 256, 0, stream>>>(W2b, b2, h1n, out);
}